// Round 13
// baseline (40.340 us; speedup 1.0000x reference)
//
#include <hip/hip_runtime.h>

typedef unsigned long long u64;

#define NPTS 8192
#define DIM  512
#define NK   64
#define KP   8              // K-split parts
#define KD   64             // dims per part
#define BM   128            // rows per tile
#define NT   (NPTS/BM)      // 64 tiles

// workspace layout (float offsets)
#define WS_DOT  0                       // [KP][NPTS][NK] = 16.8 MB
#define WS_STAT (KP * NPTS * NK)        // [KP][NPTS] float2

// ---------------------------------------------------------------------------
// GEMM: 512 blocks (64 tiles x 8 kp) x 128 threads. Tile 128x64x64.
// 8x8 microtile -> 16 ds_read_b128 per 256 FMA-instrs (L/F=1:16): LDS-pipe
// time 12.3k cyc/CU ~= 5.1us (R8/R11's 4x4 and 8x4 were 12:128 = 7.7us;
// the ratio, not bytes, is the invariant cost). Conflict-free by bank math:
//   A reads: av[i]=rows rg+16i, lanes rg=t>>3 -> 8 CONSECUTIVE rows/instr,
//            banks 4*rg distinct, 8-way broadcast over cg. pitch 17 f4.
//   B reads: bv[c]=cols cg+8c, lanes cg=t&7 -> 8 consecutive cols, free.
// One barrier. acc[8][8]+av[8]+bv[8] ~= 145 VGPR, 128 thr, NO min-waves hint.
// Partials stored [kp][pt][col]: per instr 8 pts x 8-consecutive-col 32B
// segments; the c-loop covers each 256B row fully -> L2 merges to full lines.
// Stats ride on LDS after the barrier; out[0] zeroed here (stream order).
// ---------------------------------------------------------------------------
__global__ __launch_bounds__(128) void gemm_kernel(
    const float* __restrict__ f, const int* __restrict__ cid,
    float* __restrict__ ws, float* __restrict__ out)
{
    __shared__ float4 Al4[BM * 17];   // [row][slot] 34.8 KB
    __shared__ float4 Bl4[NK * 17];   // [col][slot] 17.4 KB

    const int t     = threadIdx.x;
    const int tile  = blockIdx.x >> 3;
    const int kp    = blockIdx.x & 7;
    const int kbase = kp * KD;
    if (blockIdx.x == 0 && t == 0) out[0] = 0.f;

    // ---- stage A: (s=t&15 slot, rb=t>>4): per instr 4-8 rows x 64B segs ----
    {
        const int s = t & 15, rb = t >> 4;
        const float* fA = f + (size_t)(tile * BM + rb) * DIM + kbase + 4 * s;
        #pragma unroll
        for (int m = 0; m < 16; ++m)
            Al4[(rb + 8 * m) * 17 + s] =
                *(const float4*)(fA + (size_t)(8 * m) * DIM);
    }
    // ---- stage B: (col=t&63, q=t>>6): cid-gather, L2-hot ----
    {
        const int col = t & 63, q = t >> 6;
        const float* fB = f + (size_t)cid[col] * DIM + kbase + q * 32;
        #pragma unroll
        for (int j = 0; j < 8; ++j)
            Bl4[col * 17 + q * 8 + j] = *(const float4*)(fB + 4 * j);
    }
    __syncthreads();          // the only barrier

    // ---- per-point stats for this K-slice (thread t <-> row t) ----
    {
        float sp = 0.f, qp = 0.f;
        #pragma unroll
        for (int s2 = 0; s2 < 16; ++s2) {
            float4 v = Al4[t * 17 + s2];
            sp += (v.x + v.y) + (v.z + v.w);
            qp = fmaf(v.x, v.x, qp); qp = fmaf(v.y, v.y, qp);
            qp = fmaf(v.z, v.z, qp); qp = fmaf(v.w, v.w, qp);
        }
        ((float2*)(ws + WS_STAT))[(size_t)kp * NPTS + tile * BM + t] =
            make_float2(sp, qp);
    }

    // ---- compute: rows rg+16i (i<8), cols cg+8c (c<8) ----
    const int rg = ((t >> 3) & 7) + 8 * (t >> 6);   // wave0: 0..7, wave1: 8..15
    const int cg = t & 7;
    float acc[8][8];
    #pragma unroll
    for (int i = 0; i < 8; ++i)
        #pragma unroll
        for (int c = 0; c < 8; ++c) acc[i][c] = 0.f;

    #pragma unroll
    for (int g = 0; g < 16; ++g) {    // 16 macro-steps of 4 dims
        float4 av[8], bv[8];
        #pragma unroll
        for (int i = 0; i < 8; ++i) av[i] = Al4[(rg + 16 * i) * 17 + g];
        #pragma unroll
        for (int c = 0; c < 8; ++c) bv[c] = Bl4[(cg + 8 * c) * 17 + g];
        #pragma unroll
        for (int i = 0; i < 8; ++i)
            #pragma unroll
            for (int c = 0; c < 8; ++c) {
                acc[i][c] = fmaf(av[i].x, bv[c].x, acc[i][c]);
                acc[i][c] = fmaf(av[i].y, bv[c].y, acc[i][c]);
                acc[i][c] = fmaf(av[i].z, bv[c].z, acc[i][c]);
                acc[i][c] = fmaf(av[i].w, bv[c].w, acc[i][c]);
            }
    }

    // ---- store partials [kp][pt][col] ----
    #pragma unroll
    for (int i = 0; i < 8; ++i) {
        float* dst = ws + WS_DOT
                   + ((size_t)kp * NPTS + tile * BM + rg + 16 * i) * NK + cg;
        #pragma unroll
        for (int c = 0; c < 8; ++c) dst[8 * c] = acc[i][c];
    }
}

// ---------------------------------------------------------------------------
// Epilogue: 128 blocks x 256 threads (1024 waves); 4 threads per point
// (j = t&3 owns cols 16j..16j+15). Reads are f4 over [kp][pt][col]: per
// instr 16 pts x 256B = 4KB contiguous. Packed-key min + 2-step shfl
// combine; centroid stats gathered from point stats via cid; last-write-
// wins override; per-wave energy atomic.
// ---------------------------------------------------------------------------
__global__ __launch_bounds__(256) void epi_kernel(
    const float* __restrict__ ws, const int* __restrict__ cid,
    float* __restrict__ out)
{
    __shared__ float cqL[NK], csL[NK];
    __shared__ int   cidL[NK];

    const int t  = threadIdx.x;
    const int pt = (blockIdx.x * 256 + t) >> 2;
    const int j  = t & 3;
    const float2* st = (const float2*)(ws + WS_STAT);

    if (t < NK) {                      // centroid stats = stats of point cid[t]
        const int cr = cid[t];
        float s = 0.f, q = 0.f;
        #pragma unroll
        for (int kp = 0; kp < KP; ++kp) {
            float2 v = st[(size_t)kp * NPTS + cr]; s += v.x; q += v.y;
        }
        cqL[t] = q; csL[t] = s; cidL[t] = cr;
    }
    float s = 0.f, q = 0.f;            // this point's stats
    #pragma unroll
    for (int kp = 0; kp < KP; ++kp) {
        float2 v = st[(size_t)kp * NPTS + pt]; s += v.x; q += v.y;
    }
    __syncthreads();

    float d[16];
    #pragma unroll
    for (int c = 0; c < 16; ++c) d[c] = 0.f;
    #pragma unroll
    for (int kp = 0; kp < KP; ++kp) {
        const float4* p = (const float4*)(
            ws + WS_DOT + ((size_t)kp * NPTS + pt) * NK + 16 * j);
        #pragma unroll
        for (int s2 = 0; s2 < 4; ++s2) {
            float4 v = p[s2];
            d[4*s2+0] += v.x; d[4*s2+1] += v.y;
            d[4*s2+2] += v.z; d[4*s2+3] += v.w;
        }
    }

    u64 key = ~0ull;
    #pragma unroll
    for (int c = 0; c < 16; ++c) {
        const int col = 16 * j + c;
        float d2 = q + cqL[col] - 2.f * d[c] + 2.0e-6f * (s - csL[col])
                 + 5.12e-10f;
        float dist = sqrtf(fmaxf(d2, 0.f));
        u64 kk = (((u64)__float_as_uint(dist)) << 6) | (unsigned)col;
        key = (kk < key) ? kk : key;
    }
    {
        u64 o = __shfl_xor(key, 1); key = (o < key) ? o : key;
        o = __shfl_xor(key, 2);     key = (o < key) ? o : key;
    }

    float e = 0.f;
    if (j == 0) {
        float y = (float)(unsigned)(key & 63ull);
        for (int k = 0; k < NK; ++k)
            if (cidL[k] == pt) y = (float)k;           // last write wins
        out[1 + pt] = y;
        e = __uint_as_float((unsigned)(key >> 6));
    }
    #pragma unroll
    for (int off = 1; off < 64; off <<= 1) e += __shfl_xor(e, off);
    if ((t & 63) == 0) atomicAdd(out, -e);
}

extern "C" void kernel_launch(void* const* d_in, const int* in_sizes, int n_in,
                              void* d_out, int out_size, void* d_ws, size_t ws_size,
                              hipStream_t stream) {
    const float* f   = (const float*)d_in[0];
    const int*   cid = (const int*)d_in[1];
    float*       out = (float*)d_out;
    float*       ws  = (float*)d_ws;     // ~17 MB used

    gemm_kernel<<<NT * KP, 128, 0, stream>>>(f, cid, ws, out);
    epi_kernel<<<NPTS / 64, 256, 0, stream>>>(ws, cid, out);
}